// Round 5
// baseline (518.008 us; speedup 1.0000x reference)
//
#include <hip/hip_runtime.h>
#include <hip/hip_bf16.h>

#define TT 2048
#define BB 512
#define HH 32
#define NPAIR (TT * BB)
#define PSTRIDE (BB * HH)   // elements per t-slice of P = 16384
#define CSC 2.88539008177792681f   // 2*log2(e), folded into W/b/P

// Pin a value into a live VGPR (R9-proven variant, no memory clobber).
#define PIN(x) asm volatile("" : "+v"(x))

#if defined(__has_builtin)
#  if __has_builtin(__builtin_amdgcn_permlane16_swap)
#    define HAVE_PLSWAP 1
#  endif
#endif
#ifndef HAVE_PLSWAP
#  define HAVE_PLSWAP 0
#endif

// Unscaled tanh for the fallback kernel.
__device__ __forceinline__ float fast_tanh(float u) {
    float e = exp2f(u * CSC);
    return fmaf(__builtin_amdgcn_rcpf(e + 1.0f), -2.0f, 1.0f);
}

// DPP row-rotate by N within each 16-lane row (direct ROW_ROR:N, N=1..15).
template <int N>
__device__ __forceinline__ float dpp_ror(float v) {
    return __int_as_float(__builtin_amdgcn_mov_dpp(
        __float_as_int(v), 0x120 | N, 0xF, 0xF, false));
}
// lane xor 16 within each 32-lane group (BitMode: xor=16, and=0x1F). Fallback only.
__device__ __forceinline__ float swz_x16(float v) {
    return __int_as_float(__builtin_amdgcn_ds_swizzle(__float_as_int(v), 0x401F));
}

__device__ __forceinline__ unsigned short f2bfu(float f) {
    __hip_bfloat16 h = __float2bfloat16(f);
    return *reinterpret_cast<unsigned short*>(&h);
}
__device__ __forceinline__ short f2bf(float f) {
    __hip_bfloat16 h = __float2bfloat16(f);
    return *reinterpret_cast<short*>(&h);
}

typedef __attribute__((ext_vector_type(8))) short bf16x8;
typedef __attribute__((ext_vector_type(4))) float f32x4;

// ---------------- Pass 1: MFMA precompute, swapped operands, 64 pairs/wave -------------
__global__ __launch_bounds__(256) void precompute_mfma2(
        const int* __restrict__ x, const float* __restrict__ emb,
        const float* __restrict__ W_rnn, const float* __restrict__ b_rnn,
        __hip_bfloat16* __restrict__ P) {
    const int l  = threadIdx.x & 63;
    const int wv = (blockIdx.x * 256 + threadIdx.x) >> 6;   // global wave id
    const int m16 = l & 15;
    const int q   = l >> 4;           // quad: k-slice base q*8, C-row base q*4
    const int pair0 = wv * 64;

    bf16x8 a0, a1;
#pragma unroll
    for (int j = 0; j < 8; ++j) {
        a0[j] = f2bf(CSC * W_rnn[(q * 8 + j) * HH + m16]);
        a1[j] = f2bf(CSC * W_rnn[(q * 8 + j) * HH + m16 + 16]);
    }
    f32x4 cb0, cb1;
#pragma unroll
    for (int reg = 0; reg < 4; ++reg) {
        cb0[reg] = CSC * b_rnn[q * 4 + reg];
        cb1[reg] = CSC * b_rnn[q * 4 + reg + 16];
    }

#pragma unroll
    for (int it = 0; it < 4; ++it) {
        const int pairB = pair0 + it * 16;
        const int idx = x[pairB + m16];
        const float4* ep = (const float4*)(emb + (size_t)idx * HH + q * 8);
        float4 e0 = ep[0], e1 = ep[1];
        bf16x8 bf;
        bf[0] = f2bf(e0.x); bf[1] = f2bf(e0.y); bf[2] = f2bf(e0.z); bf[3] = f2bf(e0.w);
        bf[4] = f2bf(e1.x); bf[5] = f2bf(e1.y); bf[6] = f2bf(e1.z); bf[7] = f2bf(e1.w);

        f32x4 c0 = cb0, c1 = cb1;
        c0 = __builtin_amdgcn_mfma_f32_16x16x32_bf16(a0, bf, c0, 0, 0, 0);
        c1 = __builtin_amdgcn_mfma_f32_16x16x32_bf16(a1, bf, c1, 0, 0, 0);

        uint2 s0, s1;
        s0.x = (unsigned)f2bfu(c0[0]) | ((unsigned)f2bfu(c0[1]) << 16);
        s0.y = (unsigned)f2bfu(c0[2]) | ((unsigned)f2bfu(c0[3]) << 16);
        s1.x = (unsigned)f2bfu(c1[0]) | ((unsigned)f2bfu(c1[1]) << 16);
        s1.y = (unsigned)f2bfu(c1[2]) | ((unsigned)f2bfu(c1[3]) << 16);
        __hip_bfloat16* pp = P + (size_t)(pairB + m16) * HH + q * 4;
        *(uint2*)(pp)      = s0;
        *(uint2*)(pp + 16) = s1;
    }
}

// ---------------- Pass 2: v17 — two interleaved recurrences per wave -------------------
// Each wave owns 4 batch rows: stream0 = rows {4b,4b+1} (lane-parallel), stream1 =
// rows {4b+2,4b+3}. The streams are register-interleaved so stream1's ~94-cyc body
// issues under stream0's ~100+cyc serial tail (reduce->swap->exp2->rcp) and vice
// versa — attacks the measured ~60% dependency-stall of v14.
// State is r = rcp(1+2^u) (v15-validated fold): weights pre-scaled by -2*CSC, the
// h=1-2r constant Σ_k Wh[k][j]*CSC added to p off-chain; h reconstructed only in the
// epilogue. Exchange = per-lane permlane16_swap + select (v14-proven).
__global__ __launch_bounds__(64, 1) void rnn_seq_v17(
        const __hip_bfloat16* __restrict__ P, const float* __restrict__ W_rnn,
        const float* __restrict__ W_cls, const float* __restrict__ b_cls,
        float* __restrict__ out) {
    const int l = threadIdx.x;
    const int i = l & 15;
    const int q = (l >> 4) & 1;
    const int j = q * 16 + i;

    // Direction probe (validated R6-R16: absmax 0.0).
    int rt = __builtin_amdgcn_mov_dpp(i, 0x121, 0xF, 0xF, false);
    const int d = (rt == ((i + 1) & 15)) ? 1 : -1;

#if HAVE_PLSWAP
    // Output-order probe (per-lane: row-parity-dependent semantics possible).
    bool takeX;
    {
        unsigned lv = (unsigned)l;
        auto pr = __builtin_amdgcn_permlane16_swap(lv, lv, false, false);
        takeX = ((unsigned)pr[0] == (unsigned)(l ^ 16));
    }
#endif

    // Weights shared by both streams (same W for all batch rows). -2 fold exact.
    float wK[16], wS[16];
#pragma unroll
    for (int o = 0; o < 16; ++o) {
        const int k = q * 16 + ((i + d * o) & 15);
        wK[o] = -2.0f * CSC * W_rnn[(HH + k) * HH + j];
        wS[o] = -2.0f * CSC * W_rnn[(HH + k) * HH + ((q ^ 1) * 16 + i)];
    }
#pragma unroll
    for (int o = 0; o < 16; ++o) { PIN(wK[o]); PIN(wS[o]); }

    // WSf = CSC * sum_k Wh[k][j] (constant fold of h = 1-2r), added into p off-chain.
    float WSf = 0.0f;
#pragma unroll
    for (int k = 0; k < HH; ++k) WSf += W_rnn[(HH + k) * HH + j];
    WSf *= CSC;

    const __hip_bfloat16* gp0 = P + (size_t)blockIdx.x * 128 + l;   // rows 4b,4b+1
    const __hip_bfloat16* gp1 = gp0 + 64;                           // rows 4b+2,4b+3

    float pA0[8], pA1[8], pB0[8], pB1[8];
#pragma unroll
    for (int t = 0; t < 8; ++t) {
        pA0[t] = __bfloat162float(gp0[(size_t)t * PSTRIDE]) + WSf;
        pA1[t] = __bfloat162float(gp1[(size_t)t * PSTRIDE]) + WSf;
    }

    float r0 = 0.5f, r1 = 0.5f;   // h0 = 0 => r0 = 0.5

    auto step2 = [&](float p0, float p1) {
        // ---------- body, stream0 ----------
        float x0[16];
        x0[0] = r0;
        x0[1]  = dpp_ror<1>(r0);  x0[2]  = dpp_ror<2>(r0);  x0[3]  = dpp_ror<3>(r0);
        x0[4]  = dpp_ror<4>(r0);  x0[5]  = dpp_ror<5>(r0);  x0[6]  = dpp_ror<6>(r0);
        x0[7]  = dpp_ror<7>(r0);  x0[8]  = dpp_ror<8>(r0);  x0[9]  = dpp_ror<9>(r0);
        x0[10] = dpp_ror<10>(r0); x0[11] = dpp_ror<11>(r0); x0[12] = dpp_ror<12>(r0);
        x0[13] = dpp_ror<13>(r0); x0[14] = dpp_ror<14>(r0); x0[15] = dpp_ror<15>(r0);

        float ka0 = fmaf(x0[0], wK[0], p0);
        float ka1 = x0[1] * wK[1], ka2 = x0[2] * wK[2], ka3 = x0[3] * wK[3];
        float sa0 = x0[0] * wS[0], sa1 = x0[1] * wS[1];
        float sa2 = x0[2] * wS[2], sa3 = x0[3] * wS[3];
#pragma unroll
        for (int m = 1; m < 4; ++m) {
            ka0 = fmaf(x0[4*m+0], wK[4*m+0], ka0);
            ka1 = fmaf(x0[4*m+1], wK[4*m+1], ka1);
            ka2 = fmaf(x0[4*m+2], wK[4*m+2], ka2);
            ka3 = fmaf(x0[4*m+3], wK[4*m+3], ka3);
            sa0 = fmaf(x0[4*m+0], wS[4*m+0], sa0);
            sa1 = fmaf(x0[4*m+1], wS[4*m+1], sa1);
            sa2 = fmaf(x0[4*m+2], wS[4*m+2], sa2);
            sa3 = fmaf(x0[4*m+3], wS[4*m+3], sa3);
        }
        float send0 = (sa0 + sa1) + (sa2 + sa3);
#if HAVE_PLSWAP
        unsigned sv0 = __float_as_uint(send0);
        auto sw0 = __builtin_amdgcn_permlane16_swap(sv0, sv0, false, false);
#endif

        // ---------- body, stream1 (issues under stream0's swap/tail latency) ----------
        float x1[16];
        x1[0] = r1;
        x1[1]  = dpp_ror<1>(r1);  x1[2]  = dpp_ror<2>(r1);  x1[3]  = dpp_ror<3>(r1);
        x1[4]  = dpp_ror<4>(r1);  x1[5]  = dpp_ror<5>(r1);  x1[6]  = dpp_ror<6>(r1);
        x1[7]  = dpp_ror<7>(r1);  x1[8]  = dpp_ror<8>(r1);  x1[9]  = dpp_ror<9>(r1);
        x1[10] = dpp_ror<10>(r1); x1[11] = dpp_ror<11>(r1); x1[12] = dpp_ror<12>(r1);
        x1[13] = dpp_ror<13>(r1); x1[14] = dpp_ror<14>(r1); x1[15] = dpp_ror<15>(r1);

        float kb0 = fmaf(x1[0], wK[0], p1);
        float kb1 = x1[1] * wK[1], kb2 = x1[2] * wK[2], kb3 = x1[3] * wK[3];
        float sb0 = x1[0] * wS[0], sb1 = x1[1] * wS[1];
        float sb2 = x1[2] * wS[2], sb3 = x1[3] * wS[3];
#pragma unroll
        for (int m = 1; m < 4; ++m) {
            kb0 = fmaf(x1[4*m+0], wK[4*m+0], kb0);
            kb1 = fmaf(x1[4*m+1], wK[4*m+1], kb1);
            kb2 = fmaf(x1[4*m+2], wK[4*m+2], kb2);
            kb3 = fmaf(x1[4*m+3], wK[4*m+3], kb3);
            sb0 = fmaf(x1[4*m+0], wS[4*m+0], sb0);
            sb1 = fmaf(x1[4*m+1], wS[4*m+1], sb1);
            sb2 = fmaf(x1[4*m+2], wS[4*m+2], sb2);
            sb3 = fmaf(x1[4*m+3], wS[4*m+3], sb3);
        }
        float send1 = (sb0 + sb1) + (sb2 + sb3);
#if HAVE_PLSWAP
        unsigned sv1 = __float_as_uint(send1);
        auto sw1 = __builtin_amdgcn_permlane16_swap(sv1, sv1, false, false);
        float recv0 = takeX ? __uint_as_float((unsigned)sw0[0])
                            : __uint_as_float((unsigned)sw0[1]);
        float recv1 = takeX ? __uint_as_float((unsigned)sw1[0])
                            : __uint_as_float((unsigned)sw1[1]);
#else
        float recv0 = swz_x16(send0);
        float recv1 = swz_x16(send1);
#endif

        // ---------- tails (each stream's chain hides under the other's issue) ----------
        float u0 = ((ka0 + ka1) + (ka2 + ka3)) + recv0;
        float u1 = ((kb0 + kb1) + (kb2 + kb3)) + recv1;
        float e0 = exp2f(u0);
        float e1 = exp2f(u1);
        r0 = __builtin_amdgcn_rcpf(e0 + 1.0f);
        r1 = __builtin_amdgcn_rcpf(e1 + 1.0f);
    };

#pragma unroll 1
    for (int e = 0; e < TT / 16; ++e) {
        const int tB = e * 16 + 8;
#pragma unroll
        for (int t = 0; t < 8; ++t) {
            pB0[t] = __bfloat162float(gp0[(size_t)(tB + t) * PSTRIDE]) + WSf;
            pB1[t] = __bfloat162float(gp1[(size_t)(tB + t) * PSTRIDE]) + WSf;
        }
#pragma unroll
        for (int t = 0; t < 8; ++t) { PIN(pA0[t]); PIN(pA1[t]); }
#pragma unroll
        for (int s = 0; s < 8; ++s) step2(pA0[s], pA1[s]);

        int tA = e * 16 + 16;
        if (tA > TT - 8) tA = TT - 8;
#pragma unroll
        for (int t = 0; t < 8; ++t) {
            pA0[t] = __bfloat162float(gp0[(size_t)(tA + t) * PSTRIDE]) + WSf;
            pA1[t] = __bfloat162float(gp1[(size_t)(tA + t) * PSTRIDE]) + WSf;
        }
#pragma unroll
        for (int t = 0; t < 8; ++t) { PIN(pB0[t]); PIN(pB1[t]); }
#pragma unroll
        for (int s = 0; s < 8; ++s) step2(pB0[s], pB1[s]);
    }

    __shared__ float hf[128];
    hf[l]      = fmaf(r0, -2.0f, 1.0f);   // h = 1 - 2r
    hf[64 + l] = fmaf(r1, -2.0f, 1.0f);   // single wave: no barrier needed
    if (l < 20) {
        const int rr = l / 5, c = l % 5;
        float acc = b_cls[c];
#pragma unroll
        for (int k = 0; k < 32; ++k)
            acc = fmaf(hf[rr * 32 + k], W_cls[k * 5 + c], acc);
        out[(blockIdx.x * 4 + rr) * 5 + c] = acc;
    }
}

// ---------------- Fallback (fused) for tiny workspace ----------------------------------
__device__ __forceinline__ float rnn_step_fb(const float4 xt[8], const float wx[32],
                                             const float wh[32], float bj,
                                             float* hrow, int lane) {
    float u0 = 0.f, u1 = 0.f, u2 = 0.f, u3 = 0.f;
#pragma unroll
    for (int q = 0; q < 8; ++q) {
        u0 = fmaf(xt[q].x, wx[4*q+0], u0);
        u1 = fmaf(xt[q].y, wx[4*q+1], u1);
        u2 = fmaf(xt[q].z, wx[4*q+2], u2);
        u3 = fmaf(xt[q].w, wx[4*q+3], u3);
    }
    const float4* hp = (const float4*)hrow;
#pragma unroll
    for (int q = 0; q < 8; ++q) {
        float4 hv = hp[q];
        u0 = fmaf(hv.x, wh[4*q+0], u0);
        u1 = fmaf(hv.y, wh[4*q+1], u1);
        u2 = fmaf(hv.z, wh[4*q+2], u2);
        u3 = fmaf(hv.w, wh[4*q+3], u3);
    }
    float hn = fast_tanh(bj + ((u0 + u1) + (u2 + u3)));
    hrow[lane] = hn;
    return hn;
}

__global__ __launch_bounds__(64, 1) void rnn_seq_kernel(
        const int* __restrict__ x, const float* __restrict__ emb,
        const float* __restrict__ W_rnn, const float* __restrict__ b_rnn,
        const float* __restrict__ W_cls, const float* __restrict__ b_cls,
        float* __restrict__ out) {
    const int lane = threadIdx.x & 31;
    const int grp  = threadIdx.x >> 5;
    const int row  = blockIdx.x * 2 + grp;
    __shared__ float hbuf[2][HH];
    float wx[32], wh[32];
#pragma unroll
    for (int k = 0; k < 32; ++k) {
        wx[k] = W_rnn[k * HH + lane];
        wh[k] = W_rnn[(HH + k) * HH + lane];
    }
    const float bj = b_rnn[lane];
    hbuf[grp][lane] = 0.0f;
    float* hrow = &hbuf[grp][0];
    int i1 = x[1 * BB + row];
    float4 xcur[8], xnxt[8];
    {
        int i0 = x[0 * BB + row];
        const float4* ep = (const float4*)(emb + (size_t)i0 * HH);
#pragma unroll
        for (int q = 0; q < 8; ++q) xcur[q] = ep[q];
    }
    for (int t = 0; t < TT; t += 2) {
        int i2 = x[min(t + 2, TT - 1) * BB + row];
        {
            const float4* ep = (const float4*)(emb + (size_t)i1 * HH);
#pragma unroll
            for (int q = 0; q < 8; ++q) xnxt[q] = ep[q];
        }
        rnn_step_fb(xcur, wx, wh, bj, hrow, lane);
        i1 = x[min(t + 3, TT - 1) * BB + row];
        {
            const float4* ep = (const float4*)(emb + (size_t)i2 * HH);
#pragma unroll
            for (int q = 0; q < 8; ++q) xcur[q] = ep[q];
        }
        rnn_step_fb(xnxt, wx, wh, bj, hrow, lane);
    }
    if (lane < 5) {
        float acc = b_cls[lane];
#pragma unroll
        for (int k = 0; k < 32; ++k)
            acc = fmaf(hrow[k], W_cls[k * 5 + lane], acc);
        out[row * 5 + lane] = acc;
    }
}

extern "C" void kernel_launch(void* const* d_in, const int* in_sizes, int n_in,
                              void* d_out, int out_size, void* d_ws, size_t ws_size,
                              hipStream_t stream) {
    const int*   x     = (const int*)d_in[0];
    const float* emb   = (const float*)d_in[1];
    const float* W_rnn = (const float*)d_in[2];
    const float* b_rnn = (const float*)d_in[3];
    const float* W_cls = (const float*)d_in[4];
    const float* b_cls = (const float*)d_in[5];
    float* out = (float*)d_out;

    const size_t need16 = (size_t)NPAIR * HH * 2;   // 64 MiB (bf16 P)
    if (ws_size >= need16) {
        __hip_bfloat16* P = (__hip_bfloat16*)d_ws;
        const int pre_blocks = NPAIR / 256;         // 4096 blocks x 4 waves x 64 pairs
        precompute_mfma2<<<pre_blocks, 256, 0, stream>>>(x, emb, W_rnn, b_rnn, P);
        rnn_seq_v17<<<BB / 4, 64, 0, stream>>>(P, W_rnn, W_cls, b_cls, out);
    } else {
        rnn_seq_kernel<<<BB / 2, 64, 0, stream>>>(x, emb, W_rnn, b_rnn, W_cls, b_cls, out);
    }
}